// Round 10
// baseline (1185.800 us; speedup 1.0000x reference)
//
#include <hip/hip_runtime.h>

#define NATOM 65536
#define MNBR 12
#define NMROW (NATOM*MNBR)      // 786432
#define ORIG 92
#define NBRF 41
#define AF 64
#define HF 128
#define NCRYS 1024
#define EPSBN 1e-5f
#define NBP 48                  // padded edge width (bf16)
#define CGRID 2048
#define NTASK 16384             // 48-row tasks; 8 per block exactly

typedef __attribute__((ext_vector_type(8))) short short8;
typedef __attribute__((ext_vector_type(4))) short shortx4;
typedef __attribute__((ext_vector_type(4))) float floatx4;

__device__ __forceinline__ float softplusf_(float x){
    return fmaxf(x,0.f) + __logf(1.f + __expf(-fabsf(x)));
}
__device__ __forceinline__ float sigmoidf_(float x){
    return __builtin_amdgcn_rcpf(1.f + __expf(-x));
}
__device__ __forceinline__ short f2bf(float x){
    unsigned u = __float_as_uint(x);
    u += 0x7fffu + ((u >> 16) & 1u);   // RNE
    return (short)(u >> 16);
}
// async global->LDS DMA, 16 B per lane; LDS dest = wave-uniform base + lane*16
__device__ __forceinline__ void gl2lds16(const void* g, void* l){
    __builtin_amdgcn_global_load_lds((const __attribute__((address_space(1))) unsigned int*)g,
                                     (__attribute__((address_space(3))) unsigned int*)l, 16, 0, 0);
}

// ---------------- embedding: afea = atom_fea @ emb_w + emb_b ----------------
__global__ void k_embed(const float* __restrict__ atom_fea, const float* __restrict__ emb_w,
                        const float* __restrict__ emb_b, float* __restrict__ afea,
                        short* __restrict__ abf)
{
    __shared__ float wl[ORIG*AF];
    __shared__ float bl[AF];
    __shared__ float rows[4*ORIG];
    int tid = threadIdx.x;
    for (int i = tid; i < ORIG*AF; i += 256) wl[i] = emb_w[i];
    if (tid < AF) bl[tid] = emb_b[tid];
    __syncthreads();
    for (int t = blockIdx.x; t < NATOM/4; t += gridDim.x) {
        for (int i = tid; i < 4*ORIG; i += 256) rows[i] = atom_fea[t*4*ORIG + i];
        __syncthreads();
        int r = tid >> 6, c = tid & 63;
        float acc = bl[c];
        const float* rp = &rows[r*ORIG];
        #pragma unroll 4
        for (int k = 0; k < ORIG; ++k) acc += rp[k] * wl[k*AF + c];
        int n = t*4 + r;
        afea[n*AF + c] = acc;
        abf[n*AF + c] = f2bf(acc);
        __syncthreads();
    }
}

// ------------- one-time: nbr_fea fp32 [NM][41] -> bf16 padded [NM][48] -------------
__global__ void k_prep_nbr(const float* __restrict__ nbr_fea, short* __restrict__ nbf)
{
    int g = blockIdx.x*256 + threadIdx.x;   // NMROW*6 threads
    int row = g / 6, c = g % 6;
    const float* src = nbr_fea + (long)row*NBRF + c*8;
    short8 v = {0,0,0,0,0,0,0,0};
    if (c < 5) {
        #pragma unroll
        for (int j = 0; j < 8; ++j) v[j] = f2bf(src[j]);
    } else {
        v[0] = f2bf(src[0]);                // k=40 only
    }
    *(short8*)(nbf + (long)g*8) = v;
}

// ------------- per-layer: W fp32 [169][128] -> bf16 fragments [ks][q][c][j] -------------
__global__ void k_prep_w(const float* __restrict__ W, short* __restrict__ wt2)
{
    int g = blockIdx.x*256 + threadIdx.x;   // 24576 threads
    int j = g & 7, c = (g >> 3) & 127, q = (g >> 10) & 3, ks = g >> 12;
    int k = ks*32 + q*8 + j;
    wt2[g] = (k < 169) ? f2bf(W[k*128 + c]) : (short)0;
}

// ---------------- conv GEMM: gated = [self|nbr|edge] @ W + b ----------------
// R6 shape: 256 threads, 4 waves; wave owns 16 paired channels (filt cf, core cf+64),
// task = 48 rows. Staging per task: nbr rows (gather) + self rows via hold regs +
// ds_write; edge rows (contiguous 4608 B) via async global_load_lds DMA into the
// next LDS buffer. Double-buffered, software-pipelined, idx prefetched 2 ahead.
// LDS buffer (shorts): nbr[48x72] @0 | edge[48x48] @3456 | self[4x64] @5760 (6016).
// PASS2=0: per-channel sum/sumsq -> stats1. PASS2=1: BN1+gate, m-sum -> nsum, stats2.
template<int PASS2>
__global__ __launch_bounds__(256, 4)
void k_conv(const short* __restrict__ abf, const short* __restrict__ nbf,
            const int* __restrict__ nbr_idx, const short* __restrict__ wt2,
            const float* __restrict__ bias,
            float* __restrict__ stats1, const float* __restrict__ bn1ss,
            float* __restrict__ nsum, float* __restrict__ stats2)
{
    __shared__ __align__(16) short stg[2][6016];
    __shared__ float pbuf[PASS2 ? 4*12*17 : 4];

    int tid = threadIdx.x;
    int lane = tid & 63, wave = tid >> 6;
    int l15 = lane & 15, q = lane >> 4;
    int cf = wave*16 + l15;       // filt channel (0..63)
    int cc = 64 + cf;             // core channel

    short8 wf[6][2];
    #pragma unroll
    for (int ks = 0; ks < 6; ++ks) {
        wf[ks][0] = *(const short8*)(wt2 + ((ks*4+q)*128 + cf)*8);
        wf[ks][1] = *(const short8*)(wt2 + ((ks*4+q)*128 + cc)*8);
    }
    float bs0 = bias[cf], bs1 = bias[cc];
    float sc0=0.f, sh0=0.f, sc1=0.f, sh1=0.f;
    if (PASS2) { sc0=bn1ss[cf]; sh0=bn1ss[128+cf]; sc1=bn1ss[cc]; sh1=bn1ss[128+cc]; }

    // manual staging slots: slot0 = nbr chunks tid (rows 0-31);
    // slot1: tid<128 -> nbr chunks 256+tid (rows 32-47); 128<=tid<160 -> self chunk tid-128
    int ldso[2], gco[2], nrow0 = tid >> 3, nrow1 = 32 + (tid >> 3);
    ldso[0] = nrow0*72 + (tid & 7)*8;
    gco[0]  = (tid & 7)*8;
    if (tid < 128)      { ldso[1] = nrow1*72 + (tid & 7)*8; gco[1] = (tid & 7)*8; }
    else if (tid < 160) { int j = tid - 128; ldso[1] = 5760 + (j>>3)*64 + (j&7)*8; gco[1] = j*8; }
    else                { ldso[1] = -1; gco[1] = 0; }

    // per-wave LDS read offsets
    int nvo[3], evo[3], svo[3];
    #pragma unroll
    for (int rt = 0; rt < 3; ++rt) {
        int r = rt*16 + l15;
        nvo[rt] = r*72 + q*8;
        evo[rt] = 3456 + r*48 + q*8;
        svo[rt] = 5760 + (r/12)*64 + q*8;
    }

    float s_acc[2]={0.f,0.f}, s2_acc[2]={0.f,0.f};
    float st2s = 0.f, st2q = 0.f;
    const short8 zf = {0,0,0,0,0,0,0,0};
    float* pb = pbuf + (PASS2 ? wave*(12*17) : 0);
    const int bt = blockIdx.x;

    // ---- pipeline prologue: stage task 0 into buf0, prefetch idx(task 1) ----
    int nid0 = nbr_idx[bt*48 + nrow0];
    int nid1 = (tid < 128) ? nbr_idx[bt*48 + nrow1] : 0;
    {
        // edge DMA into buf0
        const short* eb = nbf + (long)bt*2304;
        gl2lds16(eb + wave*512 + lane*8, &stg[0][3456 + wave*512]);
        if (wave == 0 && lane < 32)
            gl2lds16(eb + 2048 + lane*8, &stg[0][3456 + 2048]);
        short8 h0 = *(const short8*)(abf + (unsigned)nid0*64u + gco[0]);
        short8 h1 = zf;
        if (tid < 128)      h1 = *(const short8*)(abf + (unsigned)nid1*64u + gco[1]);
        else if (tid < 160) h1 = *(const short8*)(abf + (unsigned)bt*256u + gco[1]);
        *(short8*)(&stg[0][0] + ldso[0]) = h0;
        if (ldso[1] >= 0) *(short8*)(&stg[0][0] + ldso[1]) = h1;
    }
    nid0 = nbr_idx[(bt+CGRID)*48 + nrow0];
    if (tid < 128) nid1 = nbr_idx[(bt+CGRID)*48 + nrow1];
    __syncthreads();

    #pragma unroll 2
    for (int k = 0; k < 8; ++k) {
        int b = bt + k*CGRID;
        short8 h0 = zf, h1 = zf;
        // ---- issue next task's loads / DMA (overlap with compute below) ----
        if (k < 7) {
            int bn = b + CGRID;
            short* db = &stg[(k + 1) & 1][0];
            const short* eb = nbf + (long)bn*2304;
            gl2lds16(eb + wave*512 + lane*8, db + 3456 + wave*512);
            if (wave == 0 && lane < 32)
                gl2lds16(eb + 2048 + lane*8, db + 3456 + 2048);
            h0 = *(const short8*)(abf + (unsigned)nid0*64u + gco[0]);
            if (tid < 128)      h1 = *(const short8*)(abf + (unsigned)nid1*64u + gco[1]);
            else if (tid < 160) h1 = *(const short8*)(abf + (unsigned)bn*256u + gco[1]);
            if (k < 6) {
                nid0 = nbr_idx[(bn+CGRID)*48 + nrow0];
                if (tid < 128) nid1 = nbr_idx[(bn+CGRID)*48 + nrow1];
            }
        }

        // ---- compute current task from LDS buffer k&1 ----
        const short* sb = &stg[k & 1][0];
        floatx4 acc[3][2];
        #pragma unroll
        for (int rt=0; rt<3; ++rt) {
            acc[rt][0] = (floatx4){bs0,bs0,bs0,bs0};
            acc[rt][1] = (floatx4){bs1,bs1,bs1,bs1};
        }
        #pragma unroll
        for (int rt = 0; rt < 3; ++rt) {
            short8 sv0 = *(const short8*)(sb + svo[rt]);
            short8 sv1 = *(const short8*)(sb + svo[rt] + 32);
            short8 nv0 = *(const short8*)(sb + nvo[rt]);
            short8 nv1 = *(const short8*)(sb + nvo[rt] + 32);
            short8 ev0 = *(const short8*)(sb + evo[rt]);
            short8 ev1 = (q < 2) ? *(const short8*)(sb + evo[rt] + 32) : zf;
            #pragma unroll
            for (int ct = 0; ct < 2; ++ct) {
                acc[rt][ct] = __builtin_amdgcn_mfma_f32_16x16x32_bf16(sv0, wf[0][ct], acc[rt][ct], 0,0,0);
                acc[rt][ct] = __builtin_amdgcn_mfma_f32_16x16x32_bf16(sv1, wf[1][ct], acc[rt][ct], 0,0,0);
                acc[rt][ct] = __builtin_amdgcn_mfma_f32_16x16x32_bf16(nv0, wf[2][ct], acc[rt][ct], 0,0,0);
                acc[rt][ct] = __builtin_amdgcn_mfma_f32_16x16x32_bf16(nv1, wf[3][ct], acc[rt][ct], 0,0,0);
                acc[rt][ct] = __builtin_amdgcn_mfma_f32_16x16x32_bf16(ev0, wf[4][ct], acc[rt][ct], 0,0,0);
                acc[rt][ct] = __builtin_amdgcn_mfma_f32_16x16x32_bf16(ev1, wf[5][ct], acc[rt][ct], 0,0,0);
            }
        }

        if (!PASS2) {
            #pragma unroll
            for (int ct=0; ct<2; ++ct)
                #pragma unroll
                for (int rt=0; rt<3; ++rt)
                    #pragma unroll
                    for (int r=0; r<4; ++r) {
                        float v = acc[rt][ct][r];
                        s_acc[ct] += v; s2_acc[ct] += v*v;
                    }
        } else {
            // 4-row partials: group g = rt*4+q holds rows g*4..g*4+3 (atom = g/3)
            #pragma unroll
            for (int rt=0; rt<3; ++rt) {
                float part = 0.f;
                #pragma unroll
                for (int r=0; r<4; ++r) {
                    float f = acc[rt][0][r]*sc0 + sh0;
                    float g = acc[rt][1][r]*sc1 + sh1;
                    part += sigmoidf_(f) * softplusf_(g);
                }
                pb[(rt*4+q)*17 + l15] = part;
            }
            // wave-private LDS: lgkmcnt ordering suffices, no barrier
            int a = lane >> 4, c16 = lane & 15;
            float s = pb[(3*a+0)*17 + c16] + pb[(3*a+1)*17 + c16] + pb[(3*a+2)*17 + c16];
            nsum[(b*4 + a)*AF + wave*16 + c16] = s;
            st2s += s; st2q += s*s;
        }

        // ---- commit next task's manual staging to the other buffer ----
        if (k < 7) {
            short* db = &stg[(k + 1) & 1][0];
            *(short8*)(db + ldso[0]) = h0;
            if (ldso[1] >= 0) *(short8*)(db + ldso[1]) = h1;
        }
        __syncthreads();   // also drains global_load_lds DMA (vmcnt before barrier)
    }

    if (!PASS2) {
        #pragma unroll
        for (int ct=0; ct<2; ++ct) {
            float s = s_acc[ct], s2 = s2_acc[ct];
            s  += __shfl_xor(s, 16);  s  += __shfl_xor(s, 32);
            s2 += __shfl_xor(s2, 16); s2 += __shfl_xor(s2, 32);
            if (q == 0) {
                int c = ct ? cc : cf;
                atomicAdd(&stats1[c], s);
                atomicAdd(&stats1[128 + c], s2);
            }
        }
    } else {
        st2s += __shfl_xor(st2s, 16); st2s += __shfl_xor(st2s, 32);
        st2q += __shfl_xor(st2q, 16); st2q += __shfl_xor(st2q, 32);
        if (q == 0) {
            atomicAdd(&stats2[cf], st2s);
            atomicAdd(&stats2[64 + cf], st2q);
        }
    }
}

__global__ void k_bn1fin(const float* __restrict__ stats1, const float* __restrict__ g,
                         const float* __restrict__ b, float* __restrict__ bn1ss)
{
    int c = threadIdx.x;
    float mean = stats1[c] * (1.f/NMROW);
    float var  = stats1[128+c] * (1.f/NMROW) - mean*mean;
    float scale = g[c] * rsqrtf(var + EPSBN);
    bn1ss[c] = scale;
    bn1ss[128+c] = b[c] - mean*scale;
}

// vectorized x4: thread handles 4 consecutive channels of one atom
__global__ void k_update(float* __restrict__ afea, short* __restrict__ abf,
                         const float* __restrict__ nsum,
                         const float* __restrict__ stats2,
                         const float* __restrict__ g2, const float* __restrict__ b2)
{
    int g = blockIdx.x*256 + threadIdx.x;   // 4096 blocks; element base g*4
    int c0 = (g*4) & 63;
    float4 ns4 = ((const float4*)nsum)[g];
    float4 a4  = ((const float4*)afea)[g];
    float o[4]; shortx4 ob;
    #pragma unroll
    for (int i = 0; i < 4; ++i) {
        int c = c0 + i;
        float mean = stats2[c] * (1.f/NATOM);
        float var  = stats2[64+c] * (1.f/NATOM) - mean*mean;
        float scale = g2[c]*rsqrtf(var + EPSBN);
        float shift = b2[c] - mean*scale;
        float ns = ((const float*)&ns4)[i]*scale + shift;
        float a = ((const float*)&a4)[i];
        float v = softplusf_(a + ns) + a;
        o[i] = v; ob[i] = f2bf(v);
    }
    ((float4*)afea)[g] = (float4){o[0],o[1],o[2],o[3]};
    *(shortx4*)(abf + (long)g*4) = ob;
}

__global__ void k_pool(const float* __restrict__ afea, const int* __restrict__ cidx,
                       float* __restrict__ pool, float* __restrict__ cnt)
{
    int g = blockIdx.x*256 + threadIdx.x;   // 1024 blocks
    int c = g & 63; int chunk = g >> 6;     // 4096 chunks x 16 atoms
    float run = 0.f, rc = 0.f; int cur = -1;
    for (int i = 0; i < 16; ++i) {
        int a = chunk*16 + i;
        int cr = cidx[a];
        float v = afea[a*64 + c];
        if (cr != cur) {
            if (cur >= 0) { atomicAdd(&pool[cur*64+c], run); if (c==0) atomicAdd(&cnt[cur], rc); }
            run = 0.f; rc = 0.f; cur = cr;
        }
        run += v; rc += 1.f;
    }
    atomicAdd(&pool[cur*64+c], run); if (c==0) atomicAdd(&cnt[cur], rc);
}

__global__ void k_head(const float* __restrict__ pool, const float* __restrict__ cnt,
                       const float* __restrict__ fc1w, const float* __restrict__ fc1b,
                       const float* __restrict__ o1w, const float* __restrict__ o1b,
                       const float* __restrict__ o2w, const float* __restrict__ o2b,
                       float* __restrict__ dout)
{
    __shared__ float spv[64], crys[128], h1[64];
    int b = blockIdx.x, tid = threadIdx.x;
    if (tid < 64) {
        float ct = fmaxf(cnt[b], 1.f);
        spv[tid] = softplusf_(pool[b*64+tid] / ct);
    }
    __syncthreads();
    float a = fc1b[tid];
    for (int k = 0; k < 64; ++k) a += spv[k] * fc1w[k*128 + tid];
    float v = softplusf_(a);
    crys[tid] = v;
    dout[NCRYS + b*128 + tid] = v;
    __syncthreads();
    if (tid < 64) {
        float a2 = o1b[tid];
        for (int k = 0; k < 128; ++k) a2 += crys[k] * o1w[k*64 + tid];
        h1[tid] = softplusf_(a2) * o2w[tid];
    }
    __syncthreads();
    if (tid == 0) {
        float s = o2b[0];
        for (int j = 0; j < 64; ++j) s += h1[j];
        dout[b] = s;
    }
}

extern "C" void kernel_launch(void* const* d_in, const int* in_sizes, int n_in,
                              void* d_out, int out_size, void* d_ws, size_t ws_size,
                              hipStream_t stream)
{
    const float* atom_fea = (const float*)d_in[0];
    const float* nbr_fea  = (const float*)d_in[1];
    const int*   nbr_idx  = (const int*)d_in[2];
    const int*   cidx     = (const int*)d_in[3];
    const float* emb_w    = (const float*)d_in[4];
    const float* emb_b    = (const float*)d_in[5];
    const float* cfw      = (const float*)d_in[6];
    const float* cfb      = (const float*)d_in[7];
    const float* bn1g     = (const float*)d_in[8];
    const float* bn1b     = (const float*)d_in[9];
    const float* bn2g     = (const float*)d_in[10];
    const float* bn2b     = (const float*)d_in[11];
    const float* fc1w     = (const float*)d_in[12];
    const float* fc1b     = (const float*)d_in[13];
    const float* o1w      = (const float*)d_in[14];
    const float* o1b      = (const float*)d_in[15];
    const float* o2w      = (const float*)d_in[16];
    const float* o2b      = (const float*)d_in[17];

    float* ws    = (float*)d_ws;
    float* afea  = ws;                         // 16 MB
    float* nsum  = ws + 4194304;               // 16 MB
    short* abf   = (short*)(ws + 8388608);     // 8 MB
    short* nbf   = (short*)(ws + 10485760);    // 75.5 MB
    short* wt2   = (short*)(ws + 29360128);    // 48 KB
    float* stats = ws + 29372416;              // 3 x 640
    float* pool  = ws + 29374336;              // 256 KB
    float* cnt   = ws + 29439872;              // 4 KB

    hipMemsetAsync(stats, 0, (1920 + 65536 + 1024)*sizeof(float), stream);

    k_prep_nbr<<<(NMROW*6)/256, 256, 0, stream>>>(nbr_fea, nbf);
    k_embed<<<2048, 256, 0, stream>>>(atom_fea, emb_w, emb_b, afea, abf);

    for (int L = 0; L < 3; ++L) {
        float* st1 = stats + L*640;
        float* ss  = st1 + 256;
        float* st2 = st1 + 512;
        k_prep_w<<<96, 256, 0, stream>>>(cfw + L*169*128, wt2);
        k_conv<0><<<CGRID, 256, 0, stream>>>(abf, nbf, nbr_idx, wt2, cfb + L*128,
                                             st1, nullptr, nullptr, nullptr);
        k_bn1fin<<<1, 128, 0, stream>>>(st1, bn1g + L*128, bn1b + L*128, ss);
        k_conv<1><<<CGRID, 256, 0, stream>>>(abf, nbf, nbr_idx, wt2, cfb + L*128,
                                             nullptr, ss, nsum, st2);
        k_update<<<4096, 256, 0, stream>>>(afea, abf, nsum, st2, bn2g + L*64, bn2b + L*64);
    }
    k_pool<<<1024, 256, 0, stream>>>(afea, cidx, pool, cnt);
    k_head<<<NCRYS, 128, 0, stream>>>(pool, cnt, fc1w, fc1b, o1w, o1b, o2w, o2b, (float*)d_out);
}

// Round 11
// 821.636 us; speedup vs baseline: 1.4432x; 1.4432x over previous
//
#include <hip/hip_runtime.h>

#define NATOM 65536
#define MNBR 12
#define NMROW (NATOM*MNBR)      // 786432
#define ORIG 92
#define NBRF 41
#define AF 64
#define HF 128
#define NCRYS 1024
#define EPSBN 1e-5f
#define NBP 48                  // padded edge width (bf16)
#define CGRID 2048
#define NTASK 16384             // 48-row tasks; 8 per block exactly

typedef __attribute__((ext_vector_type(8))) short short8;
typedef __attribute__((ext_vector_type(4))) short shortx4;
typedef __attribute__((ext_vector_type(4))) float floatx4;

__device__ __forceinline__ float softplusf_(float x){
    return fmaxf(x,0.f) + __logf(1.f + __expf(-fabsf(x)));
}
__device__ __forceinline__ float sigmoidf_(float x){
    return __builtin_amdgcn_rcpf(1.f + __expf(-x));
}
__device__ __forceinline__ short f2bf(float x){
    unsigned u = __float_as_uint(x);
    u += 0x7fffu + ((u >> 16) & 1u);   // RNE
    return (short)(u >> 16);
}
__device__ __forceinline__ unsigned packbf(float f, float g){
    return (unsigned)(unsigned short)f2bf(f) | ((unsigned)(unsigned short)f2bf(g) << 16);
}

// ---------------- embedding: afea = atom_fea @ emb_w + emb_b ----------------
__global__ void k_embed(const float* __restrict__ atom_fea, const float* __restrict__ emb_w,
                        const float* __restrict__ emb_b, float* __restrict__ afea,
                        short* __restrict__ abf)
{
    __shared__ float wl[ORIG*AF];
    __shared__ float bl[AF];
    __shared__ float rows[4*ORIG];
    int tid = threadIdx.x;
    for (int i = tid; i < ORIG*AF; i += 256) wl[i] = emb_w[i];
    if (tid < AF) bl[tid] = emb_b[tid];
    __syncthreads();
    for (int t = blockIdx.x; t < NATOM/4; t += gridDim.x) {
        for (int i = tid; i < 4*ORIG; i += 256) rows[i] = atom_fea[t*4*ORIG + i];
        __syncthreads();
        int r = tid >> 6, c = tid & 63;
        float acc = bl[c];
        const float* rp = &rows[r*ORIG];
        #pragma unroll 4
        for (int k = 0; k < ORIG; ++k) acc += rp[k] * wl[k*AF + c];
        int n = t*4 + r;
        afea[n*AF + c] = acc;
        abf[n*AF + c] = f2bf(acc);
        __syncthreads();
    }
}

// ------------- one-time: nbr_fea fp32 [NM][41] -> bf16 padded [NM][48] -------------
__global__ void k_prep_nbr(const float* __restrict__ nbr_fea, short* __restrict__ nbf)
{
    int g = blockIdx.x*256 + threadIdx.x;   // NMROW*6 threads
    int row = g / 6, c = g % 6;
    const float* src = nbr_fea + (long)row*NBRF + c*8;
    short8 v = {0,0,0,0,0,0,0,0};
    if (c < 5) {
        #pragma unroll
        for (int j = 0; j < 8; ++j) v[j] = f2bf(src[j]);
    } else {
        v[0] = f2bf(src[0]);                // k=40 only
    }
    *(short8*)(nbf + (long)g*8) = v;
}

// ------------- one-time: all 3 layers' W fp32 [169][128] -> bf16 fragments -------------
// wt2[L][ks][q][c][j]
__global__ void k_prep_w(const float* __restrict__ W, short* __restrict__ wt2)
{
    int g = blockIdx.x*256 + threadIdx.x;   // 73728 threads
    int L = g / 24576, r = g % 24576;
    int j = r & 7, c = (r >> 3) & 127, q = (r >> 10) & 3, ks = r >> 12;
    int k = ks*32 + q*8 + j;
    wt2[g] = (k < 169) ? f2bf(W[L*169*128 + k*128 + c]) : (short)0;
}

// ---------------- conv GEMM: gated = [self|nbr|edge] @ W + b ----------------
// R7-proven shape: 256 threads, 4 waves, bound 3 (NO-SPILL config — do not raise).
// MODE 0: stats1 only. MODE 1: BN1+gate+m-sum. MODE 2: stats1 + packed gated.
template<int MODE>
__global__ __launch_bounds__(256, 3)
void k_conv(const short* __restrict__ abf, const short* __restrict__ nbf,
            const int* __restrict__ nbr_idx, const short* __restrict__ wt2,
            const float* __restrict__ bias,
            float* __restrict__ stats1, const float* __restrict__ bn1ss,
            float* __restrict__ nsum, float* __restrict__ stats2,
            unsigned* __restrict__ gpair)
{
    __shared__ __align__(16) short stg[2][6432];
    __shared__ float pbuf[(MODE==1) ? 4*12*17 : 4];

    int tid = threadIdx.x;
    int lane = tid & 63, wave = tid >> 6;
    int l15 = lane & 15, q = lane >> 4;
    int cf = wave*16 + l15;
    int cc = 64 + cf;

    short8 wf[6][2];
    #pragma unroll
    for (int ks = 0; ks < 6; ++ks) {
        wf[ks][0] = *(const short8*)(wt2 + ((ks*4+q)*128 + cf)*8);
        wf[ks][1] = *(const short8*)(wt2 + ((ks*4+q)*128 + cc)*8);
    }
    float bs0 = bias[cf], bs1 = bias[cc];
    float sc0=0.f, sh0=0.f, sc1=0.f, sh1=0.f;
    if (MODE==1) { sc0=bn1ss[cf]; sh0=bn1ss[128+cf]; sc1=bn1ss[cc]; sh1=bn1ss[128+cc]; }

    int kind[3], ldso[3], nrow[3]; long gco[3];
    #pragma unroll
    for (int s = 0; s < 3; ++s) {
        int i = tid + s*256;
        if (i < 384)      { kind[s]=0; int row=i>>3, c=i&7; nrow[s]=row; ldso[s]=row*72+c*8; gco[s]=c*8; }
        else if (i < 672) { kind[s]=1; int j=i-384; int row=j/6, c=j%6; nrow[s]=0; ldso[s]=3456+row*56+c*8; gco[s]=row*48+c*8; }
        else if (i < 704) { kind[s]=2; int j=i-672; int a=j>>3, c=j&7; nrow[s]=0; ldso[s]=6144+a*72+c*8; gco[s]=a*64+c*8; }
        else              { kind[s]=3; nrow[s]=0; ldso[s]=0; gco[s]=0; }
    }
    int nvo[3], evo[3], svo[3];
    #pragma unroll
    for (int rt = 0; rt < 3; ++rt) {
        int r = rt*16 + l15;
        nvo[rt] = r*72 + q*8;
        evo[rt] = 3456 + r*56 + q*8;
        svo[rt] = 6144 + (r/12)*72 + q*8;
    }

    float s_acc[2]={0.f,0.f}, s2_acc[2]={0.f,0.f};
    float st2s = 0.f, st2q = 0.f;
    const short8 zf = {0,0,0,0,0,0,0,0};
    float* pb = pbuf + ((MODE==1) ? wave*(12*17) : 0);
    const int bt = blockIdx.x;

    int nid[3];
    short8 hold[3];
    #pragma unroll
    for (int s = 0; s < 3; ++s)
        if (kind[s]==0) nid[s] = nbr_idx[bt*48 + nrow[s]];
    #pragma unroll
    for (int s = 0; s < 3; ++s) {
        if (kind[s]==0)      hold[s] = *(const short8*)(abf + (unsigned)nid[s]*64u + gco[s]);
        else if (kind[s]==1) hold[s] = *(const short8*)(nbf + (long)bt*2304 + gco[s]);
        else if (kind[s]==2) hold[s] = *(const short8*)(abf + (unsigned)bt*256u + gco[s]);
    }
    #pragma unroll
    for (int s = 0; s < 3; ++s)
        if (kind[s]==0) nid[s] = nbr_idx[(bt+CGRID)*48 + nrow[s]];
    #pragma unroll
    for (int s = 0; s < 3; ++s)
        if (kind[s] < 3) *(short8*)(&stg[0][0] + ldso[s]) = hold[s];
    __syncthreads();

    #pragma unroll 2
    for (int k = 0; k < 8; ++k) {
        int b = bt + k*CGRID;
        if (k < 7) {
            int bn = b + CGRID;
            #pragma unroll
            for (int s = 0; s < 3; ++s) {
                if (kind[s]==0)      hold[s] = *(const short8*)(abf + (unsigned)nid[s]*64u + gco[s]);
                else if (kind[s]==1) hold[s] = *(const short8*)(nbf + (long)bn*2304 + gco[s]);
                else if (kind[s]==2) hold[s] = *(const short8*)(abf + (unsigned)bn*256u + gco[s]);
            }
            if (k < 6) {
                #pragma unroll
                for (int s = 0; s < 3; ++s)
                    if (kind[s]==0) nid[s] = nbr_idx[(bn+CGRID)*48 + nrow[s]];
            }
        }

        const short* sb = &stg[k & 1][0];
        floatx4 acc[3][2];
        #pragma unroll
        for (int rt=0; rt<3; ++rt) {
            acc[rt][0] = (floatx4){bs0,bs0,bs0,bs0};
            acc[rt][1] = (floatx4){bs1,bs1,bs1,bs1};
        }
        #pragma unroll
        for (int rt = 0; rt < 3; ++rt) {
            short8 sv0 = *(const short8*)(sb + svo[rt]);
            short8 sv1 = *(const short8*)(sb + svo[rt] + 32);
            short8 nv0 = *(const short8*)(sb + nvo[rt]);
            short8 nv1 = *(const short8*)(sb + nvo[rt] + 32);
            short8 ev0 = *(const short8*)(sb + evo[rt]);
            short8 ev1 = (q < 2) ? *(const short8*)(sb + evo[rt] + 32) : zf;
            #pragma unroll
            for (int ct = 0; ct < 2; ++ct) {
                acc[rt][ct] = __builtin_amdgcn_mfma_f32_16x16x32_bf16(sv0, wf[0][ct], acc[rt][ct], 0,0,0);
                acc[rt][ct] = __builtin_amdgcn_mfma_f32_16x16x32_bf16(sv1, wf[1][ct], acc[rt][ct], 0,0,0);
                acc[rt][ct] = __builtin_amdgcn_mfma_f32_16x16x32_bf16(nv0, wf[2][ct], acc[rt][ct], 0,0,0);
                acc[rt][ct] = __builtin_amdgcn_mfma_f32_16x16x32_bf16(nv1, wf[3][ct], acc[rt][ct], 0,0,0);
                acc[rt][ct] = __builtin_amdgcn_mfma_f32_16x16x32_bf16(ev0, wf[4][ct], acc[rt][ct], 0,0,0);
                acc[rt][ct] = __builtin_amdgcn_mfma_f32_16x16x32_bf16(ev1, wf[5][ct], acc[rt][ct], 0,0,0);
            }
        }

        if (MODE != 1) {
            #pragma unroll
            for (int ct=0; ct<2; ++ct)
                #pragma unroll
                for (int rt=0; rt<3; ++rt)
                    #pragma unroll
                    for (int r=0; r<4; ++r) {
                        float v = acc[rt][ct][r];
                        s_acc[ct] += v; s2_acc[ct] += v*v;
                    }
        }
        if (MODE == 2) {
            #pragma unroll
            for (int rt=0; rt<3; ++rt) {
                unsigned base = (unsigned)(b*48 + rt*16 + q*4)*64u + (unsigned)(wave*16 + l15);
                #pragma unroll
                for (int r=0; r<4; ++r)
                    __builtin_nontemporal_store(packbf(acc[rt][0][r], acc[rt][1][r]),
                                                gpair + base + (unsigned)r*64u);
            }
        }
        if (MODE == 1) {
            #pragma unroll
            for (int rt=0; rt<3; ++rt) {
                float part = 0.f;
                #pragma unroll
                for (int r=0; r<4; ++r) {
                    float f = acc[rt][0][r]*sc0 + sh0;
                    float g = acc[rt][1][r]*sc1 + sh1;
                    part += sigmoidf_(f) * softplusf_(g);
                }
                pb[(rt*4+q)*17 + l15] = part;
            }
            int a = lane >> 4, c16 = lane & 15;
            float s = pb[(3*a+0)*17 + c16] + pb[(3*a+1)*17 + c16] + pb[(3*a+2)*17 + c16];
            nsum[(b*4 + a)*AF + wave*16 + c16] = s;
            st2s += s; st2q += s*s;
        }

        if (k < 7) {
            short* db = &stg[(k + 1) & 1][0];
            #pragma unroll
            for (int s = 0; s < 3; ++s)
                if (kind[s] < 3) *(short8*)(db + ldso[s]) = hold[s];
        }
        __syncthreads();
    }

    if (MODE != 1) {
        #pragma unroll
        for (int ct=0; ct<2; ++ct) {
            float s = s_acc[ct], s2 = s2_acc[ct];
            s  += __shfl_xor(s, 16);  s  += __shfl_xor(s, 32);
            s2 += __shfl_xor(s2, 16); s2 += __shfl_xor(s2, 32);
            if (q == 0) {
                int c = ct ? cc : cf;
                atomicAdd(&stats1[c], s);
                atomicAdd(&stats1[128 + c], s2);
            }
        }
    } else {
        st2s += __shfl_xor(st2s, 16); st2s += __shfl_xor(st2s, 32);
        st2q += __shfl_xor(st2q, 16); st2q += __shfl_xor(st2q, 32);
        if (q == 0) {
            atomicAdd(&stats2[cf], st2s);
            atomicAdd(&stats2[64 + cf], st2q);
        }
    }
}

// -------- elementwise pass 2 (big-ws path): BN1 (folded from stats1) + gate + m-sum --------
__global__ __launch_bounds__(256, 4)
void k_gate(const unsigned* __restrict__ gpair, const float* __restrict__ stats1,
            const float* __restrict__ bn1g, const float* __restrict__ bn1b,
            float* __restrict__ nsum, float* __restrict__ stats2)
{
    __shared__ float red[2][4][64];
    int tid = threadIdx.x;
    int lane = tid & 63, wave = tid >> 6;
    // fold bn1fin: derive BN1 scale/shift for ch=lane (filt) and ch=64+lane (core)
    float m0 = stats1[lane]     * (1.f/NMROW);
    float v0 = stats1[128+lane] * (1.f/NMROW) - m0*m0;
    float scf = bn1g[lane] * rsqrtf(v0 + EPSBN);
    float shf = bn1b[lane] - m0*scf;
    float m1 = stats1[64+lane]  * (1.f/NMROW);
    float v1 = stats1[192+lane] * (1.f/NMROW) - m1*m1;
    float scc = bn1g[64+lane] * rsqrtf(v1 + EPSBN);
    float shc = bn1b[64+lane] - m1*scc;

    float st2s = 0.f, st2q = 0.f;
    int a0 = blockIdx.x*64 + wave;
    for (int j = 0; j < 16; ++j) {
        int atom = a0 + j*4;
        const unsigned* gp = gpair + (unsigned)atom*12u*64u + lane;
        unsigned u[12];
        #pragma unroll
        for (int i = 0; i < 12; ++i) u[i] = gp[i*64];
        float s = 0.f;
        #pragma unroll
        for (int i = 0; i < 12; ++i) {
            float f = __uint_as_float(u[i] << 16);
            float g = __uint_as_float(u[i] & 0xffff0000u);
            f = f*scf + shf;
            g = g*scc + shc;
            s += sigmoidf_(f) * softplusf_(g);
        }
        nsum[atom*AF + lane] = s;
        st2s += s; st2q += s*s;
    }
    red[0][wave][lane] = st2s;
    red[1][wave][lane] = st2q;
    __syncthreads();
    if (tid < 64) {
        float s  = red[0][0][tid] + red[0][1][tid] + red[0][2][tid] + red[0][3][tid];
        float s2 = red[1][0][tid] + red[1][1][tid] + red[1][2][tid] + red[1][3][tid];
        atomicAdd(&stats2[tid], s);
        atomicAdd(&stats2[64 + tid], s2);
    }
}

// bn1fin kept for the fallback (two-GEMM) path only
__global__ void k_bn1fin(const float* __restrict__ stats1, const float* __restrict__ g,
                         const float* __restrict__ b, float* __restrict__ bn1ss)
{
    int c = threadIdx.x;
    float mean = stats1[c] * (1.f/NMROW);
    float var  = stats1[128+c] * (1.f/NMROW) - mean*mean;
    float scale = g[c] * rsqrtf(var + EPSBN);
    bn1ss[c] = scale;
    bn1ss[128+c] = b[c] - mean*scale;
}

// vectorized x4 (layers 0,1): thread handles 4 consecutive channels of one atom
__global__ void k_update(float* __restrict__ afea, short* __restrict__ abf,
                         const float* __restrict__ nsum,
                         const float* __restrict__ stats2,
                         const float* __restrict__ g2, const float* __restrict__ b2)
{
    int g = blockIdx.x*256 + threadIdx.x;   // 4096 blocks; element base g*4
    int c0 = (g*4) & 63;
    float4 ns4 = ((const float4*)nsum)[g];
    float4 a4  = ((const float4*)afea)[g];
    float o[4]; shortx4 ob;
    #pragma unroll
    for (int i = 0; i < 4; ++i) {
        int c = c0 + i;
        float mean = stats2[c] * (1.f/NATOM);
        float var  = stats2[64+c] * (1.f/NATOM) - mean*mean;
        float scale = g2[c]*rsqrtf(var + EPSBN);
        float shift = b2[c] - mean*scale;
        float ns = ((const float*)&ns4)[i]*scale + shift;
        float a = ((const float*)&a4)[i];
        float v = softplusf_(a + ns) + a;
        o[i] = v; ob[i] = f2bf(v);
    }
    ((float4*)afea)[g] = (float4){o[0],o[1],o[2],o[3]};
    *(shortx4*)(abf + (long)g*4) = ob;
}

// -------- fused last-layer tail: update + crystal mean-pool + fc1 + head --------
// crystal b = atoms [b*64, b*64+64) (contiguous, count 64 exactly). 1024 blocks.
__global__ __launch_bounds__(256, 4)
void k_tail(const float* __restrict__ afea, const float* __restrict__ nsum,
            const float* __restrict__ stats2,
            const float* __restrict__ g2, const float* __restrict__ b2,
            const float* __restrict__ fc1w, const float* __restrict__ fc1b,
            const float* __restrict__ o1w, const float* __restrict__ o1b,
            const float* __restrict__ o2w, const float* __restrict__ o2b,
            float* __restrict__ dout)
{
    __shared__ float red[4][64];
    __shared__ float spv[64], crys[128], h1[64];
    int tid = threadIdx.x, lane = tid & 63, w = tid >> 6;
    int b = blockIdx.x;
    // BN2 scale/shift for channel = lane
    float mean = stats2[lane] * (1.f/NATOM);
    float var  = stats2[64+lane] * (1.f/NATOM) - mean*mean;
    float scale = g2[lane]*rsqrtf(var + EPSBN);
    float shift = b2[lane] - mean*scale;
    // update 16 atoms' channel `lane`, accumulate crystal sum
    float s = 0.f;
    int a0 = b*64 + w*16;
    for (int i = 0; i < 16; ++i) {
        int idx = (a0 + i)*64 + lane;
        float a  = afea[idx];
        float ns = nsum[idx]*scale + shift;
        s += softplusf_(a + ns) + a;
    }
    red[w][lane] = s;
    __syncthreads();
    if (tid < 64) {
        float t = red[0][tid] + red[1][tid] + red[2][tid] + red[3][tid];
        spv[tid] = softplusf_(t * (1.f/64.f));
    }
    __syncthreads();
    if (tid < 128) {
        float acc = fc1b[tid];
        #pragma unroll 4
        for (int k = 0; k < 64; ++k) acc += spv[k] * fc1w[k*128 + tid];
        float v = softplusf_(acc);
        crys[tid] = v;
        dout[NCRYS + b*128 + tid] = v;
    }
    __syncthreads();
    if (tid < 64) {
        float acc = o1b[tid];
        #pragma unroll 4
        for (int k = 0; k < 128; ++k) acc += crys[k] * o1w[k*64 + tid];
        h1[tid] = softplusf_(acc) * o2w[tid];
    }
    __syncthreads();
    if (tid == 0) {
        float sres = o2b[0];
        for (int j = 0; j < 64; ++j) sres += h1[j];
        dout[b] = sres;
    }
}

extern "C" void kernel_launch(void* const* d_in, const int* in_sizes, int n_in,
                              void* d_out, int out_size, void* d_ws, size_t ws_size,
                              hipStream_t stream)
{
    const float* atom_fea = (const float*)d_in[0];
    const float* nbr_fea  = (const float*)d_in[1];
    const int*   nbr_idx  = (const int*)d_in[2];
    const float* emb_w    = (const float*)d_in[4];
    const float* emb_b    = (const float*)d_in[5];
    const float* cfw      = (const float*)d_in[6];
    const float* cfb      = (const float*)d_in[7];
    const float* bn1g     = (const float*)d_in[8];
    const float* bn1b     = (const float*)d_in[9];
    const float* bn2g     = (const float*)d_in[10];
    const float* bn2b     = (const float*)d_in[11];
    const float* fc1w     = (const float*)d_in[12];
    const float* fc1b     = (const float*)d_in[13];
    const float* o1w      = (const float*)d_in[14];
    const float* o1b      = (const float*)d_in[15];
    const float* o2w      = (const float*)d_in[16];
    const float* o2b      = (const float*)d_in[17];

    float* ws    = (float*)d_ws;
    float* afea  = ws;                         // 16 MB
    float* nsum  = ws + 4194304;               // 16 MB
    short* abf   = (short*)(ws + 8388608);     // 8 MB
    short* nbf   = (short*)(ws + 10485760);    // 75.5 MB
    short* wt2   = (short*)(ws + 29360128);    // 3 layers x 24576 bf16 = 144 KB
    float* stats = ws + 29396992;              // 3 layers x 640
    unsigned* gpair = (unsigned*)(ws + 29440896); // 201 MB (big-ws path only)

    bool big = ws_size >= (size_t)(29440896 + 50331648) * 4;

    hipMemsetAsync(stats, 0, 1920*sizeof(float), stream);

    k_prep_nbr<<<(NMROW*6)/256, 256, 0, stream>>>(nbr_fea, nbf);
    k_prep_w<<<288, 256, 0, stream>>>(cfw, wt2);
    k_embed<<<2048, 256, 0, stream>>>(atom_fea, emb_w, emb_b, afea, abf);

    for (int L = 0; L < 3; ++L) {
        float* st1 = stats + L*640;
        float* ss  = st1 + 256;
        float* st2 = st1 + 512;
        const short* wL = wt2 + L*24576;
        if (big) {
            k_conv<2><<<CGRID, 256, 0, stream>>>(abf, nbf, nbr_idx, wL, cfb + L*128,
                                                 st1, nullptr, nullptr, nullptr, gpair);
            k_gate<<<NATOM/64, 256, 0, stream>>>(gpair, st1, bn1g + L*128, bn1b + L*128,
                                                 nsum, st2);
        } else {
            k_conv<0><<<CGRID, 256, 0, stream>>>(abf, nbf, nbr_idx, wL, cfb + L*128,
                                                 st1, nullptr, nullptr, nullptr, nullptr);
            k_bn1fin<<<1, 128, 0, stream>>>(st1, bn1g + L*128, bn1b + L*128, ss);
            k_conv<1><<<CGRID, 256, 0, stream>>>(abf, nbf, nbr_idx, wL, cfb + L*128,
                                                 nullptr, ss, nsum, st2, nullptr);
        }
        if (L < 2) {
            k_update<<<4096, 256, 0, stream>>>(afea, abf, nsum, st2, bn2g + L*64, bn2b + L*64);
        } else {
            k_tail<<<NCRYS, 256, 0, stream>>>(afea, nsum, st2, bn2g + L*64, bn2b + L*64,
                                              fc1w, fc1b, o1w, o1b, o2w, o2b, (float*)d_out);
        }
    }
}